// Round 1
// baseline (298.253 us; speedup 1.0000x reference)
//
#include <hip/hip_runtime.h>

// Fused separable 11x11 gaussian + SSIM/charb/MSE, wave-streaming form.
// R6: STRH=64 (74 steps / 64 output rows), register prefetch of the next
// input row (loads issued right after the wave_barrier, consumed by the
// NEXT step's ds_write -> global latency hidden under ~250cy of compute),
// and an h-ring: per-row horizontal results {hx,hy,hs,hp} go into an
// 11-deep register ring; the 44 vertical FMAs run only at finalize
// (64x/tile) instead of every step (was 44 FMAs x 74 steps).
// Grid is 768 blocks = exactly 3 blocks/CU -> single residency round,
// uniform finish. No __syncthreads anywhere; each wave owns a private
// double-buffered LDS row pair (ordering via wave_barrier only).
// Ring algebra: step i (u=i%11) computes h for input row r=row0-5+i into
// slot u; finalize at i>=10 produces output row o=row0+i-10 as
// v = sum_s GW[(u-s) mod 11] * h[s]  (GW symmetric => weight GW[i-j]).
// Out-of-range rows write h=0 (zero padding). Center diff kept in an
// 11-deep dring written at step i, read 5 steps later ((u+6)%11).

#define IMG    512
#define RAD    5
#define KW     11
#define STRH   64
#define NSTEP  (STRH + 2 * RAD)   // 74
#define ROWE   74                 // halo row entries (64 + 2*5)
#define PLANE  (IMG * IMG)

#define C1F  1e-4f
#define C2F  9e-4f
#define EPS2 1e-12f

#define W0 0.00102838f
#define W1 0.00759876f
#define W2 0.03600076f
#define W3 0.10936067f
#define W4 0.21300537f
#define W5 0.26601297f

__global__ __launch_bounds__(256, 4)
void CombinedLossSSIMCharbMSE_81372450390186_kernel(
    const float* __restrict__ pred,
    const float* __restrict__ target,
    float* __restrict__ out)
{
    const float GW[KW] = {W0, W1, W2, W3, W4, W5, W4, W3, W2, W1, W0};

    __shared__ float2 rb[8 * ROWE];   // 4 waves x 2 row buffers, 4736 B

    const int lane = threadIdx.x & 63;
    const int wav  = threadIdx.x >> 6;
    const int wid  = (blockIdx.x << 2) | wav;   // global wave id
    const int plane = wid >> 6;                 // 64 waves per plane
    const int tile  = (wid >> 3) & 7;           // 8 row-tiles of 64
    const int strip = wid & 7;                  // 8 col-strips of 64
    const int col0 = strip << 6;
    const int row0 = tile << 6;
    const int pbase = plane * PLANE;

    // Column geometry (constant across rows). Entry e <-> col col0-5+e.
    const int  cA  = col0 - RAD + lane;         // entries 0..63
    const bool okA = (cA >= 0) & (cA < IMG);
    const int  cAc = min(max(cA, 0), IMG - 1);
    const int  cB  = col0 + 59 + lane;          // entries 64..73 (lanes 0..9)
    const bool okB = cB < IMG;
    const int  cBc = min(cB, IMG - 1);
    const bool doB = lane < 10;

    float hrx[KW], hry[KW], hrs[KW], hrp[KW], dring[KW];
#pragma unroll
    for (int s = 0; s < KW; ++s) {
        hrx[s] = 0.f; hry[s] = 0.f; hrs[s] = 0.f; hrp[s] = 0.f; dring[s] = 0.f;
    }

    // Prologue prefetch: row for step 0 (r = row0-5; tile 0 skips, regs stay 0).
    float pAr = 0.f, tAr = 0.f, pBr = 0.f, tBr = 0.f;
    {
        const int r = row0 - RAD;
        if (r >= 0) {
            const int base = pbase + r * IMG;
            pAr = pred[base + cAc];   pAr = okA ? pAr : 0.f;
            tAr = target[base + cAc]; tAr = okA ? tAr : 0.f;
            if (doB) {
                pBr = pred[base + cBc];   pBr = okB ? pBr : 0.f;
                tBr = target[base + cBc]; tBr = okB ? tBr : 0.f;
            }
        }
    }

    for (int k = 0; k < 7; ++k) {
#pragma unroll
        for (int u = 0; u < KW; ++u) {
            const int i = k * KW + u;           // step index 0..76 (74+ cut)
            if (i >= NSTEP) break;              // wave-uniform
            const int r = row0 - RAD + i;       // input row of this step
            const bool inr = (r >= 0) && (r < IMG);   // wave-uniform

            float2* wrb = &rb[(wav * 2 + (i & 1)) * ROWE];  // dbuf parity
            if (inr) {
                // Commit the prefetched row to this step's LDS buffer.
                wrb[lane] = make_float2(pAr, tAr);
                if (doB) wrb[64 + lane] = make_float2(pBr, tBr);
                __builtin_amdgcn_wave_barrier();  // keep write->read order
            }

            // Prefetch NEXT row now; results are consumed only at the next
            // step's ds_write, so the vmcnt wait hides under this step's
            // taps + vertical + finalize (~250+ cycles of VALU issue).
            {
                const int rn = r + 1;
                if ((i + 1 < NSTEP) && rn >= 0 && rn < IMG) {   // wave-uniform
                    const int base = pbase + rn * IMG;
                    pAr = pred[base + cAc];   pAr = okA ? pAr : 0.f;
                    tAr = target[base + cAc]; tAr = okA ? tAr : 0.f;
                    if (doB) {
                        pBr = pred[base + cBc];   pBr = okB ? pBr : 0.f;
                        tBr = target[base + cBc]; tBr = okB ? tBr : 0.f;
                    }
                }
            }

            if (inr) {
                // Horizontal taps: entry lane+d = col (col0+lane) + d - 5.
                float2 c5 = make_float2(0.f, 0.f);
                float hx = 0.f, hy = 0.f, hs = 0.f, hp = 0.f;
#pragma unroll
                for (int d = 0; d < KW; ++d) {
                    const float2 t = wrb[lane + d];
                    if (d == RAD) c5 = t;
                    const float w = GW[d];
                    hx = fmaf(w, t.x, hx);
                    hy = fmaf(w, t.y, hy);
                    hs = fmaf(w, fmaf(t.x, t.x, t.y * t.y), hs);
                    hp = fmaf(w, t.x * t.y, hp);
                }
                hrx[u] = hx; hry[u] = hy; hrs[u] = hs; hrp[u] = hp;
                dring[u] = c5.x - c5.y;         // center diff, used at i+5
            } else {
                hrx[u] = 0.f; hry[u] = 0.f; hrs[u] = 0.f; hrp[u] = 0.f;
            }

            if (i >= 2 * RAD) {                 // wave-uniform finalize
                const int o = row0 + i - 2 * RAD;
                float vx = 0.f, vy = 0.f, vs = 0.f, vp = 0.f;
#pragma unroll
                for (int s2 = 0; s2 < KW; ++s2) {
                    const float w = GW[(u - s2 + KW) % KW];
                    vx = fmaf(w, hrx[s2], vx);
                    vy = fmaf(w, hry[s2], vy);
                    vs = fmaf(w, hrs[s2], vs);
                    vp = fmaf(w, hrp[s2], vp);
                }
                const float mxy = vx * vy;
                const float mu2 = fmaf(vx, vx, vy * vy);
                const float A1 = fmaf(2.f, mxy, C1F);
                const float A2 = fmaf(2.f, vp - mxy, C2F);
                const float B1 = mu2 + C1F;
                const float B2 = (vs - mu2) + C2F;
                const float ssim = (A1 * A2) * __builtin_amdgcn_rcpf(B1 * B2);
                const float d = dring[(u + 6) % KW];   // written at step i-5
                const float charb = __builtin_amdgcn_sqrtf(fmaf(d, d, EPS2));
                const float loss =
                    fmaf(0.3f, charb, fmaf(2.0f, d * d, 0.6f * (1.f - ssim)));
                out[pbase + o * IMG + col0 + lane] = loss;
            }
        }
    }
}

extern "C" void kernel_launch(void* const* d_in, const int* in_sizes, int n_in,
                              void* d_out, int out_size, void* d_ws, size_t ws_size,
                              hipStream_t stream) {
    const float* pred = (const float*)d_in[0];
    const float* target = (const float*)d_in[1];
    float* out = (float*)d_out;
    const int planes = in_sizes[0] / PLANE;     // 48

    // 64 waves per plane (8 strips x 8 tiles of 64 rows), 4 waves per block.
    dim3 grid(planes * 16);                     // 768 blocks = 3 per CU
    CombinedLossSSIMCharbMSE_81372450390186_kernel<<<grid, dim3(256), 0, stream>>>(
        pred, target, out);
}

// Round 2
// 231.492 us; speedup vs baseline: 1.2884x; 1.2884x over previous
//
#include <hip/hip_runtime.h>

// Fused separable 11x11 gaussian + SSIM/charb/MSE, wave-streaming form.
// R7: same algorithm as R6 (STRH=64, h-ring, next-row register prefetch)
// but every step is a macro expansion with a LITERAL ring index u.
// R6 regressed 99->208us because the u-loop (break + big body) did not
// fully unroll -> runtime-indexed rings -> scratch (VGPR fell 76->36).
// Here the 74 steps are: prologue steps 0..10 (literal u, row>=0 checks),
// a k=1..5 runtime loop of 11 literal-u branch-free interior steps
// (rows always valid, finalize always fires), epilogue steps 66..73
// (literal u, row<512 checks). Ring indices are compile-time everywhere.
// Per step: commit prefetched row to wave-private dbuf LDS (parity i&1,
// wave_barrier only) -> issue next row's global loads (consumed at the
// NEXT step's commit, so vmcnt hides under ~300cy of taps+finalize) ->
// 11 ds_read_b64 taps -> h-ring write -> vertical 44-FMA finalize.
// Ring algebra: step i (u=i%11) -> h slot u; finalize at i>=10 emits
// row o=row0+i-10 with weight GW[(u-s) mod 11] (GW symmetric); center
// diff dring[u] read 5 steps later at (u+6)%11. Out-of-range rows
// contribute h=0 (zero padding).

#define IMG    512
#define RAD    5
#define KW     11
#define STRH   64
#define NSTEP  (STRH + 2 * RAD)   // 74
#define ROWE   74                 // halo row entries (64 + 2*5)
#define PLANE  (IMG * IMG)

#define C1F  1e-4f
#define C2F  9e-4f
#define EPS2 1e-12f

#define W0 0.00102838f
#define W1 0.00759876f
#define W2 0.03600076f
#define W3 0.10936067f
#define W4 0.21300537f
#define W5 0.26601297f

__global__ __launch_bounds__(256, 4)
void CombinedLossSSIMCharbMSE_81372450390186_kernel(
    const float* __restrict__ pred,
    const float* __restrict__ target,
    float* __restrict__ out)
{
    const float GW[KW] = {W0, W1, W2, W3, W4, W5, W4, W3, W2, W1, W0};

    __shared__ float2 rb[8 * ROWE];   // 4 waves x 2 row buffers, 4736 B

    const int lane = threadIdx.x & 63;
    const int wav  = threadIdx.x >> 6;
    const int wid  = (blockIdx.x << 2) | wav;   // global wave id
    const int plane = wid >> 6;                 // 64 waves per plane
    const int tile  = (wid >> 3) & 7;           // 8 row-tiles of 64
    const int strip = wid & 7;                  // 8 col-strips of 64
    const int col0 = strip << 6;
    const int row0 = tile << 6;
    const int pbase = plane * PLANE;

    // Column geometry (constant across rows). Entry e <-> col col0-5+e.
    const int  cA  = col0 - RAD + lane;         // entries 0..63
    const bool okA = (cA >= 0) & (cA < IMG);
    const int  cAc = min(max(cA, 0), IMG - 1);
    const int  cB  = col0 + 59 + lane;          // entries 64..73 (lanes 0..9)
    const bool okB = cB < IMG;
    const int  cBc = min(cB, IMG - 1);
    const bool doB = lane < 10;

    float hrx[KW], hry[KW], hrs[KW], hrp[KW], dring[KW];
#pragma unroll
    for (int s = 0; s < KW; ++s) {
        hrx[s] = 0.f; hry[s] = 0.f; hrs[s] = 0.f; hrp[s] = 0.f; dring[s] = 0.f;
    }

    float pAr = 0.f, tAr = 0.f, pBr = 0.f, tBr = 0.f;   // prefetch regs

#define LOAD_ROW(rr) do {                                                   \
        const int _base = pbase + (rr) * IMG;                               \
        pAr = pred[_base + cAc];   pAr = okA ? pAr : 0.f;                   \
        tAr = target[_base + cAc]; tAr = okA ? tAr : 0.f;                   \
        if (doB) {                                                          \
            pBr = pred[_base + cBc];   pBr = okB ? pBr : 0.f;               \
            tBr = target[_base + cBc]; tBr = okB ? tBr : 0.f;               \
        }                                                                   \
    } while (0)

#define COMMIT(par) do {                                                    \
        float2* _w = &rb[(((wav) << 1) | (par)) * ROWE];                    \
        _w[lane] = make_float2(pAr, tAr);                                   \
        if (doB) _w[64 + lane] = make_float2(pBr, tBr);                     \
        __builtin_amdgcn_wave_barrier();  /* keep write->read order */      \
    } while (0)

#define TAPS(uu, par) do {                                                  \
        const float2* _rd = &rb[(((wav) << 1) | (par)) * ROWE];             \
        float _hx = 0.f, _hy = 0.f, _hs = 0.f, _hp = 0.f;                   \
        float2 _c5 = make_float2(0.f, 0.f);                                 \
        _Pragma("unroll")                                                   \
        for (int _d = 0; _d < KW; ++_d) {                                   \
            const float2 _t = _rd[lane + _d];                               \
            if (_d == RAD) _c5 = _t;                                        \
            const float _w = GW[_d];                                        \
            _hx = fmaf(_w, _t.x, _hx);                                      \
            _hy = fmaf(_w, _t.y, _hy);                                      \
            _hs = fmaf(_w, fmaf(_t.x, _t.x, _t.y * _t.y), _hs);             \
            _hp = fmaf(_w, _t.x * _t.y, _hp);                               \
        }                                                                   \
        hrx[uu] = _hx; hry[uu] = _hy; hrs[uu] = _hs; hrp[uu] = _hp;         \
        dring[uu] = _c5.x - _c5.y;     /* center diff, used at step i+5 */  \
    } while (0)

#define ZERO_H(uu) do {                                                     \
        hrx[uu] = 0.f; hry[uu] = 0.f; hrs[uu] = 0.f; hrp[uu] = 0.f;         \
    } while (0)

#define FINALIZE(uu, oo) do {                                               \
        float _vx = 0.f, _vy = 0.f, _vs = 0.f, _vp = 0.f;                   \
        _Pragma("unroll")                                                   \
        for (int _s = 0; _s < KW; ++_s) {                                   \
            const float _w = GW[((uu) - _s + KW) % KW];                     \
            _vx = fmaf(_w, hrx[_s], _vx);                                   \
            _vy = fmaf(_w, hry[_s], _vy);                                   \
            _vs = fmaf(_w, hrs[_s], _vs);                                   \
            _vp = fmaf(_w, hrp[_s], _vp);                                   \
        }                                                                   \
        const float _mxy = _vx * _vy;                                       \
        const float _mu2 = fmaf(_vx, _vx, _vy * _vy);                       \
        const float _A1 = fmaf(2.f, _mxy, C1F);                             \
        const float _A2 = fmaf(2.f, _vp - _mxy, C2F);                       \
        const float _B1 = _mu2 + C1F;                                       \
        const float _B2 = (_vs - _mu2) + C2F;                               \
        const float _ssim = (_A1 * _A2) * __builtin_amdgcn_rcpf(_B1 * _B2); \
        const float _dd = dring[((uu) + 6) % KW];  /* written step i-5 */   \
        const float _ch = __builtin_amdgcn_sqrtf(fmaf(_dd, _dd, EPS2));     \
        out[pbase + (oo) * IMG + col0 + lane] =                             \
            fmaf(0.3f, _ch, fmaf(2.0f, _dd * _dd, 0.6f * (1.f - _ssim)));   \
    } while (0)

    // ---- prologue: steps i = 0..10 (u = i), row r = row0-5+i -------------
    if (row0 > 0) LOAD_ROW(row0 - RAD);   // prefetch for step 0

#define STEP_PRO(uu) do {                                                   \
        const bool _inr = (row0 - RAD + (uu)) >= 0;      /* wave-uniform */ \
        if (_inr) COMMIT((uu) & 1);                                         \
        if ((row0 - RAD + (uu) + 1) >= 0) LOAD_ROW(row0 - RAD + (uu) + 1);  \
        if (_inr) TAPS(uu, (uu) & 1); else ZERO_H(uu);                      \
    } while (0)

    STEP_PRO(0); STEP_PRO(1); STEP_PRO(2); STEP_PRO(3); STEP_PRO(4);
    STEP_PRO(5); STEP_PRO(6); STEP_PRO(7); STEP_PRO(8); STEP_PRO(9);
    STEP_PRO(10);
    FINALIZE(10, row0);                    // first output row at i = 10

    // ---- interior: k = 1..5, steps i = 11..65 — branch-free --------------
    for (int k = 1; k <= 5; ++k) {
        const int rnext = row0 - RAD + k * KW + 1;  // prefetch row at +uu
        const int obase = row0 + k * KW - 10;       // output row at +uu
        const int kp = k & 1;                       // i parity = kp^(uu&1)
#define STEP_FULL(uu) do {                                                  \
        COMMIT(kp ^ ((uu) & 1));                                            \
        LOAD_ROW(rnext + (uu));                                             \
        TAPS(uu, kp ^ ((uu) & 1));                                          \
        FINALIZE(uu, obase + (uu));                                         \
    } while (0)
        STEP_FULL(0); STEP_FULL(1); STEP_FULL(2); STEP_FULL(3);
        STEP_FULL(4); STEP_FULL(5); STEP_FULL(6); STEP_FULL(7);
        STEP_FULL(8); STEP_FULL(9); STEP_FULL(10);
#undef STEP_FULL
    }

    // ---- epilogue: steps i = 66..73 (u = 0..7), row r = row0+61+u --------
#define STEP_EPI(uu) do {                                                   \
        const bool _inr = (row0 + 61 + (uu)) < IMG;      /* wave-uniform */ \
        if (_inr) COMMIT((uu) & 1);         /* i=66+uu, parity = uu&1 */    \
        if (((uu) < 7) && (row0 + 62 + (uu)) < IMG)                         \
            LOAD_ROW(row0 + 62 + (uu));                                     \
        if (_inr) TAPS(uu, (uu) & 1); else ZERO_H(uu);                      \
        FINALIZE(uu, row0 + 56 + (uu));                                     \
    } while (0)

    STEP_EPI(0); STEP_EPI(1); STEP_EPI(2); STEP_EPI(3);
    STEP_EPI(4); STEP_EPI(5); STEP_EPI(6); STEP_EPI(7);
#undef STEP_EPI
#undef STEP_PRO
#undef FINALIZE
#undef ZERO_H
#undef TAPS
#undef COMMIT
#undef LOAD_ROW
}

extern "C" void kernel_launch(void* const* d_in, const int* in_sizes, int n_in,
                              void* d_out, int out_size, void* d_ws, size_t ws_size,
                              hipStream_t stream) {
    const float* pred = (const float*)d_in[0];
    const float* target = (const float*)d_in[1];
    float* out = (float*)d_out;
    const int planes = in_sizes[0] / PLANE;     // 48

    // 64 waves per plane (8 strips x 8 tiles of 64 rows), 4 waves per block.
    dim3 grid(planes * 16);                     // 768 blocks = 3 per CU
    CombinedLossSSIMCharbMSE_81372450390186_kernel<<<grid, dim3(256), 0, stream>>>(
        pred, target, out);
}

// Round 3
// 183.787 us; speedup vs baseline: 1.6228x; 1.2596x over previous
//
#include <hip/hip_runtime.h>

// Fused separable 11x11 gaussian + SSIM/charb/MSE, wave-streaming form.
// R8: R7 body verbatim with __launch_bounds__(256, 2).
// R7 (launch_bounds(256,4), VGPR budget 128) spilled: VGPR_Count=64 with
// +66 MB scratch writes (WRITE_SIZE 116.7 MB vs 50.3 MB output) and
// +26 MB scratch refetches. R5 carried the SAME 55-float ring footprint
// at VGPR=76 with zero spill under (256,2). The 2nd launch_bounds arg is
// the allocator budget lever: (256,2) -> 256-reg budget, no spill needed.
// Grid stays 768 = 3 blocks/CU (3 waves/SIMD, needs only VGPR<=168).
//
// Algorithm (unchanged from R7): STRH=64, 74 steps per 64 output rows.
// Per step: commit prefetched row to wave-private double-buffered LDS row
// (parity i&1, wave_barrier only, no __syncthreads) -> issue NEXT row's
// global loads (consumed at the next step's commit, so vmcnt waits hide
// under ~300cy of taps+finalize) -> 11 ds_read_b64 horizontal taps for
// {x, y, x^2+y^2, x*y} -> h-ring slot u -> vertical 44-FMA finalize
// (only once per output row). All ring indices are macro-literal.
// Ring algebra: step i (u=i%11) -> h slot u; finalize at i>=10 emits row
// o=row0+i-10 with weight GW[(u-s) mod 11] (GW symmetric); center diff
// dring[u] read 5 steps later at (u+6)%11. Out-of-range rows give h=0.

#define IMG    512
#define RAD    5
#define KW     11
#define STRH   64
#define NSTEP  (STRH + 2 * RAD)   // 74
#define ROWE   74                 // halo row entries (64 + 2*5)
#define PLANE  (IMG * IMG)

#define C1F  1e-4f
#define C2F  9e-4f
#define EPS2 1e-12f

#define W0 0.00102838f
#define W1 0.00759876f
#define W2 0.03600076f
#define W3 0.10936067f
#define W4 0.21300537f
#define W5 0.26601297f

__global__ __launch_bounds__(256, 2)
void CombinedLossSSIMCharbMSE_81372450390186_kernel(
    const float* __restrict__ pred,
    const float* __restrict__ target,
    float* __restrict__ out)
{
    const float GW[KW] = {W0, W1, W2, W3, W4, W5, W4, W3, W2, W1, W0};

    __shared__ float2 rb[8 * ROWE];   // 4 waves x 2 row buffers, 4736 B

    const int lane = threadIdx.x & 63;
    const int wav  = threadIdx.x >> 6;
    const int wid  = (blockIdx.x << 2) | wav;   // global wave id
    const int plane = wid >> 6;                 // 64 waves per plane
    const int tile  = (wid >> 3) & 7;           // 8 row-tiles of 64
    const int strip = wid & 7;                  // 8 col-strips of 64
    const int col0 = strip << 6;
    const int row0 = tile << 6;
    const int pbase = plane * PLANE;

    // Column geometry (constant across rows). Entry e <-> col col0-5+e.
    const int  cA  = col0 - RAD + lane;         // entries 0..63
    const bool okA = (cA >= 0) & (cA < IMG);
    const int  cAc = min(max(cA, 0), IMG - 1);
    const int  cB  = col0 + 59 + lane;          // entries 64..73 (lanes 0..9)
    const bool okB = cB < IMG;
    const int  cBc = min(cB, IMG - 1);
    const bool doB = lane < 10;

    float hrx[KW], hry[KW], hrs[KW], hrp[KW], dring[KW];
#pragma unroll
    for (int s = 0; s < KW; ++s) {
        hrx[s] = 0.f; hry[s] = 0.f; hrs[s] = 0.f; hrp[s] = 0.f; dring[s] = 0.f;
    }

    float pAr = 0.f, tAr = 0.f, pBr = 0.f, tBr = 0.f;   // prefetch regs

#define LOAD_ROW(rr) do {                                                   \
        const int _base = pbase + (rr) * IMG;                               \
        pAr = pred[_base + cAc];   pAr = okA ? pAr : 0.f;                   \
        tAr = target[_base + cAc]; tAr = okA ? tAr : 0.f;                   \
        if (doB) {                                                          \
            pBr = pred[_base + cBc];   pBr = okB ? pBr : 0.f;               \
            tBr = target[_base + cBc]; tBr = okB ? tBr : 0.f;               \
        }                                                                   \
    } while (0)

#define COMMIT(par) do {                                                    \
        float2* _w = &rb[(((wav) << 1) | (par)) * ROWE];                    \
        _w[lane] = make_float2(pAr, tAr);                                   \
        if (doB) _w[64 + lane] = make_float2(pBr, tBr);                     \
        __builtin_amdgcn_wave_barrier();  /* keep write->read order */      \
    } while (0)

#define TAPS(uu, par) do {                                                  \
        const float2* _rd = &rb[(((wav) << 1) | (par)) * ROWE];             \
        float _hx = 0.f, _hy = 0.f, _hs = 0.f, _hp = 0.f;                   \
        float2 _c5 = make_float2(0.f, 0.f);                                 \
        _Pragma("unroll")                                                   \
        for (int _d = 0; _d < KW; ++_d) {                                   \
            const float2 _t = _rd[lane + _d];                               \
            if (_d == RAD) _c5 = _t;                                        \
            const float _w = GW[_d];                                        \
            _hx = fmaf(_w, _t.x, _hx);                                      \
            _hy = fmaf(_w, _t.y, _hy);                                      \
            _hs = fmaf(_w, fmaf(_t.x, _t.x, _t.y * _t.y), _hs);             \
            _hp = fmaf(_w, _t.x * _t.y, _hp);                               \
        }                                                                   \
        hrx[uu] = _hx; hry[uu] = _hy; hrs[uu] = _hs; hrp[uu] = _hp;         \
        dring[uu] = _c5.x - _c5.y;     /* center diff, used at step i+5 */  \
    } while (0)

#define ZERO_H(uu) do {                                                     \
        hrx[uu] = 0.f; hry[uu] = 0.f; hrs[uu] = 0.f; hrp[uu] = 0.f;         \
    } while (0)

#define FINALIZE(uu, oo) do {                                               \
        float _vx = 0.f, _vy = 0.f, _vs = 0.f, _vp = 0.f;                   \
        _Pragma("unroll")                                                   \
        for (int _s = 0; _s < KW; ++_s) {                                   \
            const float _w = GW[((uu) - _s + KW) % KW];                     \
            _vx = fmaf(_w, hrx[_s], _vx);                                   \
            _vy = fmaf(_w, hry[_s], _vy);                                   \
            _vs = fmaf(_w, hrs[_s], _vs);                                   \
            _vp = fmaf(_w, hrp[_s], _vp);                                   \
        }                                                                   \
        const float _mxy = _vx * _vy;                                       \
        const float _mu2 = fmaf(_vx, _vx, _vy * _vy);                       \
        const float _A1 = fmaf(2.f, _mxy, C1F);                             \
        const float _A2 = fmaf(2.f, _vp - _mxy, C2F);                       \
        const float _B1 = _mu2 + C1F;                                       \
        const float _B2 = (_vs - _mu2) + C2F;                               \
        const float _ssim = (_A1 * _A2) * __builtin_amdgcn_rcpf(_B1 * _B2); \
        const float _dd = dring[((uu) + 6) % KW];  /* written step i-5 */   \
        const float _ch = __builtin_amdgcn_sqrtf(fmaf(_dd, _dd, EPS2));     \
        out[pbase + (oo) * IMG + col0 + lane] =                             \
            fmaf(0.3f, _ch, fmaf(2.0f, _dd * _dd, 0.6f * (1.f - _ssim)));   \
    } while (0)

    // ---- prologue: steps i = 0..10 (u = i), row r = row0-5+i -------------
    if (row0 > 0) LOAD_ROW(row0 - RAD);   // prefetch for step 0

#define STEP_PRO(uu) do {                                                   \
        const bool _inr = (row0 - RAD + (uu)) >= 0;      /* wave-uniform */ \
        if (_inr) COMMIT((uu) & 1);                                         \
        if ((row0 - RAD + (uu) + 1) >= 0) LOAD_ROW(row0 - RAD + (uu) + 1);  \
        if (_inr) TAPS(uu, (uu) & 1); else ZERO_H(uu);                      \
    } while (0)

    STEP_PRO(0); STEP_PRO(1); STEP_PRO(2); STEP_PRO(3); STEP_PRO(4);
    STEP_PRO(5); STEP_PRO(6); STEP_PRO(7); STEP_PRO(8); STEP_PRO(9);
    STEP_PRO(10);
    FINALIZE(10, row0);                    // first output row at i = 10

    // ---- interior: k = 1..5, steps i = 11..65 — branch-free --------------
    for (int k = 1; k <= 5; ++k) {
        const int rnext = row0 - RAD + k * KW + 1;  // prefetch row at +uu
        const int obase = row0 + k * KW - 10;       // output row at +uu
        const int kp = k & 1;                       // i parity = kp^(uu&1)
#define STEP_FULL(uu) do {                                                  \
        COMMIT(kp ^ ((uu) & 1));                                            \
        LOAD_ROW(rnext + (uu));                                             \
        TAPS(uu, kp ^ ((uu) & 1));                                          \
        FINALIZE(uu, obase + (uu));                                         \
    } while (0)
        STEP_FULL(0); STEP_FULL(1); STEP_FULL(2); STEP_FULL(3);
        STEP_FULL(4); STEP_FULL(5); STEP_FULL(6); STEP_FULL(7);
        STEP_FULL(8); STEP_FULL(9); STEP_FULL(10);
#undef STEP_FULL
    }

    // ---- epilogue: steps i = 66..73 (u = 0..7), row r = row0+61+u --------
#define STEP_EPI(uu) do {                                                   \
        const bool _inr = (row0 + 61 + (uu)) < IMG;      /* wave-uniform */ \
        if (_inr) COMMIT((uu) & 1);         /* i=66+uu, parity = uu&1 */    \
        if (((uu) < 7) && (row0 + 62 + (uu)) < IMG)                         \
            LOAD_ROW(row0 + 62 + (uu));                                     \
        if (_inr) TAPS(uu, (uu) & 1); else ZERO_H(uu);                      \
        FINALIZE(uu, row0 + 56 + (uu));                                     \
    } while (0)

    STEP_EPI(0); STEP_EPI(1); STEP_EPI(2); STEP_EPI(3);
    STEP_EPI(4); STEP_EPI(5); STEP_EPI(6); STEP_EPI(7);
#undef STEP_EPI
#undef STEP_PRO
#undef FINALIZE
#undef ZERO_H
#undef TAPS
#undef COMMIT
#undef LOAD_ROW
}

extern "C" void kernel_launch(void* const* d_in, const int* in_sizes, int n_in,
                              void* d_out, int out_size, void* d_ws, size_t ws_size,
                              hipStream_t stream) {
    const float* pred = (const float*)d_in[0];
    const float* target = (const float*)d_in[1];
    float* out = (float*)d_out;
    const int planes = in_sizes[0] / PLANE;     // 48

    // 64 waves per plane (8 strips x 8 tiles of 64 rows), 4 waves per block.
    dim3 grid(planes * 16);                     // 768 blocks = 3 per CU
    CombinedLossSSIMCharbMSE_81372450390186_kernel<<<grid, dim3(256), 0, stream>>>(
        pred, target, out);
}